// Round 8
// baseline (343.583 us; speedup 1.0000x reference)
//
#include <hip/hip_runtime.h>

// FixedKAN round 7 (resubmit after broker timeout): split-bf16 3-product MFMA,
// compiler-scheduled waits.
//  - G1 stages raw f32 x via global_load_lds, splits hi/lo in-register
//    (x-split prep kernel eliminated).
//  - h / p intermediates stored as packed u32 (h<<16|l): half the store
//    instrs, half the staging loads downstream.
//  - K-loop has NO hand lgkmcnt/sched_barrier: plain loads + MFMAs, the
//    compiler inserts fine-grained counted waits (m97 pattern).
//  - 5 launches total: prep_gemm_sk, prep_all, G1, G3, G4.
// GEMM core: A=Ah+Al, B=Bh+Bl bf16; acc += AhBh + AhBl + AlBh (f32 MFMA).

typedef __attribute__((ext_vector_type(8))) short short8;
typedef __attribute__((ext_vector_type(4))) float f32x4;
typedef __attribute__((ext_vector_type(4))) unsigned uint32x4;
typedef unsigned short ushort_t;

#define GAS(p) ((const __attribute__((address_space(1))) void*)(p))
#define LAS(p) ((__attribute__((address_space(3))) void*)(p))

__device__ __forceinline__ void split2(float f, ushort_t& h, ushort_t& l) {
    const unsigned u = __float_as_uint(f);
    h = (ushort_t)(u >> 16);                              // truncate hi
    const float hf = __uint_as_float(u & 0xFFFF0000u);
    l = (ushort_t)(__float_as_uint(f - hf) >> 16);        // truncate residual
}

// ---------------------------------------------------------------- prep kernels
// split-K fp32 GEMM: Cp[z] partial of C[m][n] = sum_k A[m*K+k]*W[n*K+k]
constexpr int PKT = 16;
__global__ __launch_bounds__(256)
void prep_gemm_sk(const float* __restrict__ A, const float* __restrict__ W,
                  float* __restrict__ Cp, int M, int N, int K, int KS) {
    __shared__ float As[PKT][68];
    __shared__ float Bs[PKT][68];
    const int tid = threadIdx.x;
    const int bn = blockIdx.x, bm = blockIdx.y, bz = blockIdx.z;
    const int kc = K / KS, k0 = bz * kc;
    const int tx = tid & 15, ty = tid >> 4;
    float acc[4][4];
#pragma unroll
    for (int i = 0; i < 4; ++i)
#pragma unroll
        for (int j = 0; j < 4; ++j) acc[i][j] = 0.f;
    const float* Ab = A + (size_t)(bm * 64) * K + k0;
    const float* Wb = W + (size_t)(bn * 64) * K + k0;
    const int sr = tid >> 2;
    const int sc = (tid & 3) * 4;
    for (int kt = 0; kt < kc; kt += PKT) {
        const float4 va = *(const float4*)(Ab + (size_t)sr * K + kt + sc);
        As[sc + 0][sr] = va.x; As[sc + 1][sr] = va.y; As[sc + 2][sr] = va.z; As[sc + 3][sr] = va.w;
        const float4 vb = *(const float4*)(Wb + (size_t)sr * K + kt + sc);
        Bs[sc + 0][sr] = vb.x; Bs[sc + 1][sr] = vb.y; Bs[sc + 2][sr] = vb.z; Bs[sc + 3][sr] = vb.w;
        __syncthreads();
#pragma unroll
        for (int k = 0; k < PKT; ++k) {
            const float4 a4 = *(const float4*)&As[k][ty * 4];
            const float4 b4 = *(const float4*)&Bs[k][tx * 4];
            const float a[4] = {a4.x, a4.y, a4.z, a4.w};
            const float b[4] = {b4.x, b4.y, b4.z, b4.w};
#pragma unroll
            for (int i = 0; i < 4; ++i)
#pragma unroll
                for (int j = 0; j < 4; ++j) acc[i][j] = fmaf(a[i], b[j], acc[i][j]);
        }
        __syncthreads();
    }
    float* Cb = Cp + (size_t)bz * M * N + (size_t)(bm * 64 + ty * 4) * N + bn * 64 + tx * 4;
#pragma unroll
    for (int i = 0; i < 4; ++i)
        *(float4*)(Cb + (size_t)i * N) = make_float4(acc[i][0], acc[i][1], acc[i][2], acc[i][3]);
}

// fused: w1-split [1024 blocks] + m2 combine-split [256] + cW2 tsplit [256]
//        + bias2eff [64]  => grid 1600
__global__ __launch_bounds__(256)
void prep_all(const float* __restrict__ w1, ushort_t* __restrict__ w1h, ushort_t* __restrict__ w1l,
              const float* __restrict__ m2p, ushort_t* __restrict__ m2h, ushort_t* __restrict__ m2l,
              const float* __restrict__ cW2, ushort_t* __restrict__ cw2h, ushort_t* __restrict__ cw2l,
              const float* __restrict__ cb1, const float* __restrict__ w2,
              const float* __restrict__ b2, float* __restrict__ b2e) {
    const int bid = blockIdx.x;
    if (bid < 1024) {                      // split w1 (1024*1024 f32, as float4)
        const int i = bid * 256 + threadIdx.x;
        const float4 v = ((const float4*)w1)[i];
        ushort4 h, l;
        split2(v.x, h.x, l.x); split2(v.y, h.y, l.y);
        split2(v.z, h.z, l.z); split2(v.w, h.w, l.w);
        ((ushort4*)w1h)[i] = h;
        ((ushort4*)w1l)[i] = l;
    } else if (bid < 1280) {               // combine KS=4 partials of m2, split
        const int i = (bid - 1024) * 256 + threadIdx.x;   // n4 = 65536
        float4 s = ((const float4*)m2p)[i];
#pragma unroll
        for (int z = 1; z < 4; ++z) {
            const float4 v = ((const float4*)m2p)[(size_t)z * 65536 + i];
            s.x += v.x; s.y += v.y; s.z += v.z; s.w += v.w;
        }
        ushort4 h, l;
        split2(s.x, h.x, l.x); split2(s.y, h.y, l.y);
        split2(s.z, h.z, l.z); split2(s.w, h.w, l.w);
        ((ushort4*)m2h)[i] = h;
        ((ushort4*)m2l)[i] = l;
    } else if (bid < 1536) {               // transpose-split cW2 [256,256]
        const int i = (bid - 1280) * 256 + threadIdx.x;
        const int r = i >> 8, c = i & 255;
        ushort_t h, l;
        split2(cW2[r * 256 + c], h, l);
        cw2h[c * 256 + r] = h;
        cw2l[c * 256 + r] = l;
    } else {                               // bias2eff[n] = dot(cb1, w2[n,:]) + b2[n]
        const int wave = threadIdx.x >> 6, lane = threadIdx.x & 63;
        const int n = (bid - 1536) * 4 + wave;
        const float4* row = (const float4*)(w2 + (size_t)n * 1024);
        const float4* c4  = (const float4*)cb1;
        float s = 0.f;
#pragma unroll
        for (int i = 0; i < 4; ++i) {
            const int idx = lane + i * 64;
            const float4 a = row[idx], c = c4[idx];
            s += a.x * c.x + a.y * c.y + a.z * c.z + a.w * c.w;
        }
#pragma unroll
        for (int off = 32; off; off >>= 1) s += __shfl_down(s, off);
        if (lane == 0) b2e[n] = s + b2[n];
    }
}

// ================================================================ G1 kernel
// 256x256 tile, BK=32, 512 thr (8 waves 2Mx4N), wave tile 128x64 (8x4 frags).
// A staged as RAW f32 x: LDS [set][g][half][256 rows][4 f32], split in-reg.
// B staged as pre-split bf16 hi/lo: [set][hl][g][256 rows][8 bf16].
// All LDS reads: 16-lane group covers 256B contiguous -> conflict-free,
// and all global_load_lds destinations are linear (wave-uniform base + lane*16).
// Schedule: stage(next) -> plain reads + MFMAs (compiler-inserted counted
// lgkmcnt) -> vmcnt(0) -> one barrier per K-tile.
__global__ __launch_bounds__(512, 2)
void kan_g1(const float* __restrict__ Xf,
            const ushort_t* __restrict__ Bhg,
            const ushort_t* __restrict__ Blg,
            const float* __restrict__ bias,
            const float* __restrict__ coeffs,
            unsigned* __restrict__ Cpk,
            int M, int N, int K)
{
    __shared__ __align__(16) float    Asf[2][4][2][256 * 4];   // 64 KB
    __shared__ __align__(16) ushort_t Bsh[2][2][4][256 * 8];   // 64 KB

    const int tid  = threadIdx.x;
    const int lane = tid & 63;
    const int wave = tid >> 6;

    // bijective XCD swizzle (nwg = 256, %8==0)
    const int gx  = gridDim.x;
    const int nwg = gx * gridDim.y;
    int wg = blockIdx.y * gx + blockIdx.x;
    wg = (wg & 7) * (nwg >> 3) + (wg >> 3);
    const int bn = wg % gx;
    const int bm = wg / gx;

    const int wm = wave >> 2;        // 0..1  (M half)
    const int wn = wave & 3;         // 0..3  (N quarter)
    const int lr = lane & 15;
    const int lg = lane >> 4;

    const int sg  = wave & 3;              // staged k-granule
    const int r0a = (wave >> 2) * 128;     // staged row-chunk base
    const size_t aRow0 = (size_t)bm * 256;
    const size_t bRow0 = (size_t)bn * 256;

    f32x4 acc[8][4];
#pragma unroll
    for (int m = 0; m < 8; ++m)
#pragma unroll
        for (int n = 0; n < 4; ++n) acc[m][n] = f32x4{0.f, 0.f, 0.f, 0.f};

    auto stageA = [&](int s, int kt) {
#pragma unroll
        for (int rc = 0; rc < 2; ++rc)
#pragma unroll
            for (int h = 0; h < 2; ++h) {
                const int r0 = r0a + rc * 64;
                const float* src = Xf + (aRow0 + r0 + lane) * (size_t)K + kt + sg * 8 + h * 4;
                __builtin_amdgcn_global_load_lds(GAS(src), LAS(&Asf[s][sg][h][r0 * 4]), 16, 0, 0);
            }
    };
    auto stageB = [&](int s, int kt) {
#pragma unroll
        for (int rc = 0; rc < 2; ++rc)
#pragma unroll
            for (int hl = 0; hl < 2; ++hl) {
                const int r0 = r0a + rc * 64;
                const ushort_t* src = (hl ? Blg : Bhg) + (bRow0 + r0 + lane) * (size_t)K + kt + sg * 8;
                __builtin_amdgcn_global_load_lds(GAS(src), LAS(&Bsh[s][hl][sg][r0 * 8]), 16, 0, 0);
            }
    };

    // prologue: stage tile 0 into set 0
    stageA(0, 0); stageB(0, 0);
    asm volatile("s_waitcnt vmcnt(0)" ::: "memory");
    __syncthreads();

    const int nt = K >> 5;
    for (int t = 0; t < nt; ++t) {
        const int cur = t & 1;
        const bool more = (t + 1) < nt;

        if (more) { stageA(cur ^ 1, (t + 1) << 5); stageB(cur ^ 1, (t + 1) << 5); }

        // B fragments (read once, live for both halves)
        short8 bh[4], bl[4];
#pragma unroll
        for (int n = 0; n < 4; ++n) {
            const int row = wn * 64 + n * 16 + lr;
            bh[n] = *(const short8*)&Bsh[cur][0][lg][row * 8];
            bl[n] = *(const short8*)&Bsh[cur][1][lg][row * 8];
        }
#pragma unroll
        for (int half = 0; half < 2; ++half) {
            short8 ah[4], al[4];
#pragma unroll
            for (int m = 0; m < 4; ++m) {
                const int row = wm * 128 + (half * 4 + m) * 16 + lr;
                const f32x4 lo4 = *(const f32x4*)&Asf[cur][lg][0][row * 4];
                const f32x4 hi4 = *(const f32x4*)&Asf[cur][lg][1][row * 4];
#pragma unroll
                for (int e = 0; e < 4; ++e) {
                    ushort_t h, l;
                    split2(lo4[e], h, l); ah[m][e] = (short)h;     al[m][e] = (short)l;
                    split2(hi4[e], h, l); ah[m][4 + e] = (short)h; al[m][4 + e] = (short)l;
                }
            }
#pragma unroll
            for (int m = 0; m < 4; ++m)
#pragma unroll
                for (int n = 0; n < 4; ++n) {
                    const int am = half * 4 + m;
                    acc[am][n] = __builtin_amdgcn_mfma_f32_16x16x32_bf16(ah[m], bh[n], acc[am][n], 0, 0, 0);
                    acc[am][n] = __builtin_amdgcn_mfma_f32_16x16x32_bf16(ah[m], bl[n], acc[am][n], 0, 0, 0);
                    acc[am][n] = __builtin_amdgcn_mfma_f32_16x16x32_bf16(al[m], bh[n], acc[am][n], 0, 0, 0);
                }
        }

        if (more) {
            asm volatile("s_waitcnt vmcnt(0)" ::: "memory");
            __syncthreads();
        }
    }

    // ---- epilogue: bias + cheb, store packed u32 (h<<16|l).
    // C/D layout: col = lane&15, row = (lane>>4)*4 + j
    const int gm0 = bm * 256 + wm * 128;
    const int gn0 = bn * 256 + wn * 64;
#pragma unroll
    for (int n = 0; n < 4; ++n) {
        const int colg = gn0 + n * 16 + lr;
        const float bia = bias[colg];
        float cf[8];
        {
            const float4 u0 = *(const float4*)(coeffs + (size_t)colg * 8);
            const float4 u1 = *(const float4*)(coeffs + (size_t)colg * 8 + 4);
            cf[0] = u0.x; cf[1] = u0.y; cf[2] = u0.z; cf[3] = u0.w;
            cf[4] = u1.x; cf[5] = u1.y; cf[6] = u1.z; cf[7] = u1.w;
        }
#pragma unroll
        for (int m = 0; m < 8; ++m) {
            const int rowb = gm0 + m * 16 + lg * 4;
#pragma unroll
            for (int j = 0; j < 4; ++j) {
                const float alpha = acc[m][n][j] + bia;
                float tm2 = 1.f, tm1 = alpha;
                float v = fmaf(cf[1], alpha, cf[0]);
#pragma unroll
                for (int d = 2; d < 8; ++d) {
                    const float tch = 2.f * alpha * tm1 - tm2;
                    v = fmaf(cf[d], tch, v);
                    tm2 = tm1; tm1 = tch;
                }
                ushort_t h, l2;
                split2(v, h, l2);
                Cpk[(size_t)(rowb + j) * N + colg] = ((unsigned)h << 16) | l2;
            }
        }
    }
}

// ================================================================ 128^2 kernel (G3/G4)
// A staged as packed u32 (h<<16|l): LDS [set][g][half][128 rows][4 u32],
// unpacked in-register (shift/and). B pre-split bf16 hi/lo. 64 KB LDS dbuf.
template<bool CHEB, bool OUT_F32>
__global__ __launch_bounds__(256, 2)
void kan_pk(const unsigned* __restrict__ Apg,
            const ushort_t* __restrict__ Bhg,
            const ushort_t* __restrict__ Blg,
            const float* __restrict__ bias,
            const float* __restrict__ coeffs,
            float* __restrict__ Cf,
            unsigned* __restrict__ Cpk,
            int M, int N, int K)
{
    __shared__ __align__(16) unsigned Apk[2][4][2][128 * 4];   // 32 KB
    __shared__ __align__(16) ushort_t Bsh[2][2][4][128 * 8];   // 32 KB

    const int tid  = threadIdx.x;
    const int lane = tid & 63;
    const int wave = tid >> 6;

    const int gx = gridDim.x;
    const int nwg = gx * gridDim.y;
    int wg = blockIdx.y * gx + blockIdx.x;
    wg = (wg & 7) * (nwg >> 3) + (wg >> 3);
    const int bn = wg % gx;
    const int bm = wg / gx;

    const int wm = wave >> 1, wn = wave & 1;
    const int lr = lane & 15;
    const int lg = lane >> 4;

    f32x4 acc[4][4];
#pragma unroll
    for (int m = 0; m < 4; ++m)
#pragma unroll
        for (int n = 0; n < 4; ++n) acc[m][n] = f32x4{0.f, 0.f, 0.f, 0.f};

    const size_t aRow0 = (size_t)(bm * 128);
    const size_t bRow0 = (size_t)(bn * 128);
    const int sg = wave;

    auto stage = [&](int s, int kt) {
#pragma unroll
        for (int rc = 0; rc < 2; ++rc) {
            const int r0 = rc * 64;
#pragma unroll
            for (int h = 0; h < 2; ++h) {
                const unsigned* srcA = Apg + (aRow0 + r0 + lane) * (size_t)K + kt + sg * 8 + h * 4;
                __builtin_amdgcn_global_load_lds(GAS(srcA), LAS(&Apk[s][sg][h][r0 * 4]), 16, 0, 0);
            }
#pragma unroll
            for (int hl = 0; hl < 2; ++hl) {
                const ushort_t* srcB = (hl ? Blg : Bhg) + (bRow0 + r0 + lane) * (size_t)K + kt + sg * 8;
                __builtin_amdgcn_global_load_lds(GAS(srcB), LAS(&Bsh[s][hl][sg][r0 * 8]), 16, 0, 0);
            }
        }
    };

    stage(0, 0);
    asm volatile("s_waitcnt vmcnt(0)" ::: "memory");
    __syncthreads();

    const int nt = K >> 5;
    for (int t = 0; t < nt; ++t) {
        const int cur = t & 1;
        const bool more = (t + 1) < nt;

        if (more) stage(cur ^ 1, (t + 1) << 5);

        short8 bh[4], bl[4];
#pragma unroll
        for (int n = 0; n < 4; ++n) {
            const int row = wn * 64 + n * 16 + lr;
            bh[n] = *(const short8*)&Bsh[cur][0][lg][row * 8];
            bl[n] = *(const short8*)&Bsh[cur][1][lg][row * 8];
        }
        short8 ah[4], al[4];
#pragma unroll
        for (int m = 0; m < 4; ++m) {
            const int row = wm * 64 + m * 16 + lr;
            const uint32x4 lo4 = *(const uint32x4*)&Apk[cur][lg][0][row * 4];
            const uint32x4 hi4 = *(const uint32x4*)&Apk[cur][lg][1][row * 4];
#pragma unroll
            for (int e = 0; e < 4; ++e) {
                ah[m][e]     = (short)(lo4[e] >> 16); al[m][e]     = (short)(lo4[e] & 0xFFFFu);
                ah[m][4 + e] = (short)(hi4[e] >> 16); al[m][4 + e] = (short)(hi4[e] & 0xFFFFu);
            }
        }
#pragma unroll
        for (int m = 0; m < 4; ++m)
#pragma unroll
            for (int n = 0; n < 4; ++n) {
                acc[m][n] = __builtin_amdgcn_mfma_f32_16x16x32_bf16(ah[m], bh[n], acc[m][n], 0, 0, 0);
                acc[m][n] = __builtin_amdgcn_mfma_f32_16x16x32_bf16(ah[m], bl[n], acc[m][n], 0, 0, 0);
                acc[m][n] = __builtin_amdgcn_mfma_f32_16x16x32_bf16(al[m], bh[n], acc[m][n], 0, 0, 0);
            }

        if (more) {
            asm volatile("s_waitcnt vmcnt(0)" ::: "memory");
            __syncthreads();
        }
    }

    const int gm0 = bm * 128 + wm * 64;
    const int gn0 = bn * 128 + wn * 64;
#pragma unroll
    for (int n = 0; n < 4; ++n) {
        const int colg = gn0 + n * 16 + lr;
        const float bia = bias[colg];
        float cf[8];
        if constexpr (CHEB) {
            const float4 u0 = *(const float4*)(coeffs + (size_t)colg * 8);
            const float4 u1 = *(const float4*)(coeffs + (size_t)colg * 8 + 4);
            cf[0] = u0.x; cf[1] = u0.y; cf[2] = u0.z; cf[3] = u0.w;
            cf[4] = u1.x; cf[5] = u1.y; cf[6] = u1.z; cf[7] = u1.w;
        }
#pragma unroll
        for (int m = 0; m < 4; ++m) {
            const int rowb = gm0 + m * 16 + lg * 4;
#pragma unroll
            for (int j = 0; j < 4; ++j) {
                const float alpha = acc[m][n][j] + bia;
                float v;
                if constexpr (CHEB) {
                    float tm2 = 1.f, tm1 = alpha;
                    v = fmaf(cf[1], alpha, cf[0]);
#pragma unroll
                    for (int d = 2; d < 8; ++d) {
                        const float t2 = 2.f * alpha * tm1 - tm2;
                        v = fmaf(cf[d], t2, v);
                        tm2 = tm1; tm1 = t2;
                    }
                } else {
                    v = alpha;
                }
                const size_t o = (size_t)(rowb + j) * N + colg;
                if constexpr (OUT_F32) {
                    Cf[o] = v;
                } else {
                    ushort_t h, l2;
                    split2(v, h, l2);
                    Cpk[o] = ((unsigned)h << 16) | l2;
                }
            }
        }
    }
}

// ---------------------------------------------------------------- launch
extern "C" void kernel_launch(void* const* d_in, const int* in_sizes, int n_in,
                              void* d_out, int out_size, void* d_ws, size_t ws_size,
                              hipStream_t stream) {
    const float* x       = (const float*)d_in[0];
    const float* w1      = (const float*)d_in[1];
    const float* b1      = (const float*)d_in[2];
    const float* coeffs1 = (const float*)d_in[3];
    const float* cW1     = (const float*)d_in[4];
    const float* cb1     = (const float*)d_in[5];
    const float* w2      = (const float*)d_in[6];
    const float* b2      = (const float*)d_in[7];
    const float* coeffs2 = (const float*)d_in[8];
    const float* cW2     = (const float*)d_in[9];
    const float* cb2     = (const float*)d_in[10];

    constexpr int B  = 16384;
    constexpr int D1 = 1024;
    constexpr int D2 = 256;
    constexpr int KS = 4;

    char* w = (char*)d_ws;
    size_t off = 0;
    auto alloc = [&](size_t bytes) { char* p = w + off; off += (bytes + 255) & ~(size_t)255; return p; };
    unsigned* hp   = (unsigned*)alloc((size_t)B * D1 * 4);   // packed n1
    unsigned* ppk  = (unsigned*)alloc((size_t)B * D2 * 4);   // packed p
    ushort_t* w1h  = (ushort_t*)alloc((size_t)D1 * D1 * 2);
    ushort_t* w1l  = (ushort_t*)alloc((size_t)D1 * D1 * 2);
    float*    m2p  = (float*)alloc((size_t)KS * D2 * D1 * 4);
    ushort_t* m2h  = (ushort_t*)alloc((size_t)D2 * D1 * 2);
    ushort_t* m2l  = (ushort_t*)alloc((size_t)D2 * D1 * 2);
    ushort_t* cw2h = (ushort_t*)alloc((size_t)D2 * D2 * 2);
    ushort_t* cw2l = (ushort_t*)alloc((size_t)D2 * D2 * 2);
    float*    b2e  = (float*)alloc(D2 * 4);

    // ---- prep (2 launches)
    prep_gemm_sk<<<dim3(D1 / 64, D2 / 64, KS), dim3(256), 0, stream>>>(w2, cW1, m2p, D2, D1, D1, KS);
    prep_all<<<dim3(1600), dim3(256), 0, stream>>>(w1, w1h, w1l, m2p, m2h, m2l,
                                                   cW2, cw2h, cw2l, cb1, w2, b2, b2e);

    // ---- main pipeline
    // G1: n1 = cheb1(x @ w1^T + b1) -> hp (packed)
    kan_g1<<<dim3(D1 / 256, B / 256), dim3(512), 0, stream>>>(
        x, w1h, w1l, b1, coeffs1, hp, B, D1, D1);
    // G3: p = cheb2(n1 @ M2T^T + bias2eff) -> ppk (packed)
    kan_pk<true, false><<<dim3(D2 / 128, B / 128), dim3(256), 0, stream>>>(
        hp, m2h, m2l, b2e, coeffs2, nullptr, ppk, B, D2, D1);
    // G4: out = p @ cW2 + cb2 -> d_out (f32)
    kan_pk<false, true><<<dim3(D2 / 128, B / 128), dim3(256), 0, stream>>>(
        ppk, cw2h, cw2l, cb2, nullptr, (float*)d_out, nullptr, B, D2, D2);
}